// Round 5
// baseline (273.256 us; speedup 1.0000x reference)
//
#include <hip/hip_runtime.h>
#include <stdint.h>

typedef uint32_t u32;
typedef uint64_t u64;
typedef uint8_t  u8;

#define KEY_MIN   0x3C000000u   /* conf = max softmax >= 1/C = 0.01 > 2^-7 */
#define SUBSHIFT  12
#define NBUCK     14336         /* (0x3F800000 - 0x3C000000) >> 12 */
#define SUBRANGE  4096
#define NBINS     20
#define NB        19
#define K1BLK     2048

__device__ __forceinline__ u32 bucket_of(u32 key) {
    if (key < KEY_MIN) return 0u;
    u32 b = (key - KEY_MIN) >> SUBSHIFT;
    return b < (u32)NBUCK ? b : (u32)(NBUCK - 1);
}

// ---------------- K1 (C==100): 16 lanes/row, grid-stride + register prefetch --
__global__ __launch_bounds__(256) void k1_conf100(
        const float* __restrict__ logits, const int* __restrict__ labels,
        u32* __restrict__ keys, u8* __restrict__ accb, u32* __restrict__ hist,
        int N) {
    int lane = threadIdx.x & 63;
    int wid  = (blockIdx.x * (blockDim.x >> 6)) + (threadIdx.x >> 6);
    int g    = lane >> 4;
    int sub  = lane & 15;
    int gid  = wid * 4 + g;                       // group id; wave = 4 consecutive rows
    int G    = (gridDim.x * blockDim.x) >> 4;     // total 16-lane groups
    bool has2 = sub < 9;                          // 25 float4 per row: sub and sub+16
    const float4 NEG = make_float4(-3.4e38f, -3.4e38f, -3.4e38f, -3.4e38f);

    int r = gid;
    if (r >= N) return;
    const float4* rp = (const float4*)(logits + (size_t)r * 100);
    float4 a0 = rp[sub];
    float4 a1 = has2 ? rp[sub + 16] : NEG;

    while (true) {
        int rn = r + G;
        bool more = rn < N;
        // issue next row's loads BEFORE this row's reduction (keeps VMEM busy)
        const float4* rq = (const float4*)(logits + (size_t)(more ? rn : 0) * 100);
        float4 b0 = rq[sub];
        float4 b1 = has2 ? rq[sub + 16] : NEG;

        // in-lane max+argmax (FIRST max: strict >, ascending order)
        float m = a0.x; int am = 4 * sub;
        if (a0.y > m) { m = a0.y; am = 4 * sub + 1; }
        if (a0.z > m) { m = a0.z; am = 4 * sub + 2; }
        if (a0.w > m) { m = a0.w; am = 4 * sub + 3; }
        int c2 = 64 + 4 * sub;
        if (a1.x > m) { m = a1.x; am = c2; }
        if (a1.y > m) { m = a1.y; am = c2 + 1; }
        if (a1.z > m) { m = a1.z; am = c2 + 2; }
        if (a1.w > m) { m = a1.w; am = c2 + 3; }
        #pragma unroll
        for (int off = 8; off >= 1; off >>= 1) {
            float om = __shfl_xor(m, off);
            int   oa = __shfl_xor(am, off);
            if (om > m || (om == m && oa < am)) { m = om; am = oa; }
        }
        float s = __expf(a0.x - m) + __expf(a0.y - m) + __expf(a0.z - m) + __expf(a0.w - m);
        if (has2) s += __expf(a1.x - m) + __expf(a1.y - m) + __expf(a1.z - m) + __expf(a1.w - m);
        #pragma unroll
        for (int off = 8; off >= 1; off >>= 1) s += __shfl_xor(s, off);

        if (sub == 0) {
            float conf = 1.0f / s;
            u32 key = __float_as_uint(conf);
            keys[r] = key;
            accb[r] = (labels[r] == am) ? (u8)1 : (u8)0;
            atomicAdd(&hist[bucket_of(key)], 1u);
        }
        if (!more) break;
        r = rn; a0 = b0; a1 = b1;
    }
}

// ---------------- K1 generic fallback -----------------------------------------
__global__ __launch_bounds__(256) void k1_generic(
        const float* __restrict__ logits, const int* __restrict__ labels,
        u32* __restrict__ keys, u8* __restrict__ accb, u32* __restrict__ hist,
        int N, int C) {
    for (int i = blockIdx.x * blockDim.x + threadIdx.x; i < N;
         i += gridDim.x * blockDim.x) {
        const float* row = logits + (size_t)i * (size_t)C;
        float m = -3.4e38f, s = 0.f;
        int am = 0;
        for (int c = 0; c < C; c++) {
            float v = row[c];
            float nm = fmaxf(m, v); am = (v > m) ? c : am;
            s = s * __expf(m - nm) + __expf(v - nm); m = nm;
        }
        float conf = 1.0f / s;
        u32 key = __float_as_uint(conf);
        keys[i] = key;
        accb[i] = (labels[i] == am) ? (u8)1 : (u8)0;
        atomicAdd(&hist[bucket_of(key)], 1u);
    }
}

// meta: 0..18 bBucket | 19..37 bOff | 38..56 Kkey
// ---------------- K2: LDS-staged scan of hist, find boundary buckets ----------
__global__ __launch_bounds__(1024) void k2_scan(
        const u32* __restrict__ hist, u32* __restrict__ meta, u32 W) {
    __shared__ u32 lh[NBUCK];     // 56 KB
    __shared__ u32 sp[1024];      // 4 KB
    int t = threadIdx.x;
    // coalesced stage: 14 sweeps of 1024
    #pragma unroll
    for (int k = 0; k < NBUCK / 1024; k++) lh[k * 1024 + t] = hist[k * 1024 + t];
    __syncthreads();
    const int PER = NBUCK / 1024;  // 14
    u32 s = 0;
    #pragma unroll
    for (int k = 0; k < PER; k++) s += lh[t * PER + k];
    sp[t] = s; __syncthreads();
    for (int d = 1; d < 1024; d <<= 1) {
        u32 v = (t >= d) ? sp[t - d] : 0u;
        __syncthreads(); sp[t] += v; __syncthreads();
    }
    u32 cum = sp[t] - s;  // exclusive prefix over this thread's buckets
    for (int k = 0; k < PER; k++) {
        u32 c = lh[t * PER + k];
        if (c) {
            for (int j = 0; j < NB; j++) {
                u32 r = (u32)(j + 1) * W;
                if (cum < r && r <= cum + c) {
                    meta[j] = (u32)(t * PER + k);   // boundary bucket
                    meta[NB + j] = r - cum;         // count of bucket below boundary
                }
            }
        }
        cum += c;
    }
}

// ---------------- K3: sub-histogram (low 12 bits) of boundary buckets ---------
__global__ __launch_bounds__(256) void k3_subhist(
        const u32* __restrict__ keys, const u32* __restrict__ meta,
        u32* __restrict__ subhist, int N) {
    __shared__ u32 sB[NB];
    if (threadIdx.x < NB) sB[threadIdx.x] = meta[threadIdx.x];
    __syncthreads();
    int total4 = N >> 2;
    const uint4* k4 = (const uint4*)keys;
    for (int i = blockIdx.x * blockDim.x + threadIdx.x; i < total4;
         i += gridDim.x * blockDim.x) {
        uint4 kv = k4[i];
        u32 ks[4] = {kv.x, kv.y, kv.z, kv.w};
        #pragma unroll
        for (int e = 0; e < 4; e++) {
            u32 b = bucket_of(ks[e]);
            #pragma unroll
            for (int j = 0; j < NB; j++)
                if (b == sB[j])
                    atomicAdd(&subhist[j * SUBRANGE + (ks[e] & (SUBRANGE - 1))], 1u);
        }
    }
    for (int i = (total4 << 2) + blockIdx.x * blockDim.x + threadIdx.x; i < N;
         i += gridDim.x * blockDim.x) {
        u32 k = keys[i];
        u32 b = bucket_of(k);
        for (int j = 0; j < NB; j++)
            if (b == sB[j])
                atomicAdd(&subhist[j * SUBRANGE + (k & (SUBRANGE - 1))], 1u);
    }
}

// ---------------- K4: resolve exact threshold keys (19 blocks x 256) ----------
__global__ __launch_bounds__(256) void k4_resolve(
        const u32* __restrict__ subhist, u32* __restrict__ meta) {
    int j = blockIdx.x;
    int t = threadIdx.x;
    __shared__ u32 sh[256];
    const uint4* s4 = (const uint4*)(subhist + j * SUBRANGE);
    uint4 v[4];
    #pragma unroll
    for (int q = 0; q < 4; q++) v[q] = s4[t * 4 + q];   // elems t*16 .. t*16+15
    u32 tsum = 0;
    #pragma unroll
    for (int q = 0; q < 4; q++) tsum += v[q].x + v[q].y + v[q].z + v[q].w;
    sh[t] = tsum; __syncthreads();
    for (int d = 1; d < 256; d <<= 1) {
        u32 x = (t >= d) ? sh[t - d] : 0u;
        __syncthreads(); sh[t] += x; __syncthreads();
    }
    u32 run = sh[t] - tsum;
    u32 off = meta[NB + j];
    u32 bkt = meta[j];
    #pragma unroll
    for (int q = 0; q < 4; q++) {
        u32 e[4] = {v[q].x, v[q].y, v[q].z, v[q].w};
        #pragma unroll
        for (int c = 0; c < 4; c++) {
            if (run < off && off <= run + e[c])
                meta[2 * NB + j] = KEY_MIN + (bkt << SUBSHIFT) + (u32)(t * 16 + q * 4 + c);
            run += e[c];
        }
    }
}

// ---------------- K7: per-bin accumulation + fused final ECE ------------------
__global__ __launch_bounds__(256) void k7_accum(
        const u32* __restrict__ keys, const u8* __restrict__ accb,
        const u32* __restrict__ meta, u64* __restrict__ confQ,
        u32* __restrict__ accCnt, u32* __restrict__ done,
        float* __restrict__ out, int N, u32 W) {
    __shared__ unsigned long long lc[4][NBINS];
    __shared__ u32 la[4][NBINS];
    __shared__ u32 sK[NB];
    __shared__ u32 isLast;
    int t = threadIdx.x;
    int w = t >> 6;
    if (t < 4 * NBINS) { lc[t / NBINS][t % NBINS] = 0ull; la[t / NBINS][t % NBINS] = 0u; }
    if (t == 0) isLast = 0u;
    if (t < NB) sK[t] = meta[2 * NB + t];
    __syncthreads();
    int total4 = N >> 2;
    const uint4*  k4 = (const uint4*)keys;
    const uchar4* a4 = (const uchar4*)accb;
    for (int i = blockIdx.x * blockDim.x + t; i < total4; i += gridDim.x * blockDim.x) {
        uint4  kv = k4[i];
        uchar4 av = a4[i];
        u32 ks[4] = {kv.x, kv.y, kv.z, kv.w};
        u32 as[4] = {av.x, av.y, av.z, av.w};
        #pragma unroll
        for (int e = 0; e < 4; e++) {
            int bin = 0;
            #pragma unroll
            for (int j = 0; j < NB; j++) bin += (ks[e] > sK[j]) ? 1 : 0;
            u64 q = (u64)(__uint_as_float(ks[e]) * 4294967296.0f);  // exact shift
            atomicAdd(&lc[w][bin], (unsigned long long)q);
            atomicAdd(&la[w][bin], as[e]);
        }
    }
    for (int i = (total4 << 2) + blockIdx.x * blockDim.x + t; i < N;
         i += gridDim.x * blockDim.x) {
        u32 k = keys[i];
        int bin = 0;
        for (int j = 0; j < NB; j++) bin += (k > sK[j]) ? 1 : 0;
        u64 q = (u64)(__uint_as_float(k) * 4294967296.0f);
        atomicAdd(&lc[w][bin], (unsigned long long)q);
        atomicAdd(&la[w][bin], (u32)accb[i]);
    }
    __syncthreads();
    if (t < NBINS) {
        unsigned long long cq = lc[0][t] + lc[1][t] + lc[2][t] + lc[3][t];
        u32 ac = la[0][t] + la[1][t] + la[2][t] + la[3][t];
        if (cq) atomicAdd((unsigned long long*)&confQ[t], cq);  // device scope
        if (ac) atomicAdd(&accCnt[t], ac);
    }
    __syncthreads();
    if (t == 0) {
        __threadfence();
        u32 old = __hip_atomic_fetch_add(done, 1u, __ATOMIC_ACQ_REL, __HIP_MEMORY_SCOPE_AGENT);
        if (old == gridDim.x - 1) isLast = 1u;
    }
    __syncthreads();
    if (isLast && t == 0) {
        double ece = 0.0;
        for (int b = 0; b < NBINS; b++) {
            u64 cq = __hip_atomic_load(&confQ[b], __ATOMIC_RELAXED, __HIP_MEMORY_SCOPE_AGENT);
            u32 ac = __hip_atomic_load(&accCnt[b], __ATOMIC_RELAXED, __HIP_MEMORY_SCOPE_AGENT);
            double cm = (double)cq * (1.0 / 4294967296.0) / (double)W;
            double am = (double)ac / (double)W;
            ece += fabs(cm - am);
            out[1 + b] = (float)am;
        }
        out[0] = (float)(ece * (double)W / (double)N);
    }
}

extern "C" void kernel_launch(void* const* d_in, const int* in_sizes, int n_in,
                              void* d_out, int out_size, void* d_ws, size_t ws_size,
                              hipStream_t stream) {
    const float* logits = (const float*)d_in[0];
    const int*   labels = (const int*)d_in[1];
    int N = in_sizes[1];
    int C = in_sizes[0] / N;
    float* out = (float*)d_out;

    u8* ws = (u8*)d_ws;
    u32* keys = (u32*)ws;                                    // 4N
    u8*  accb = ws + (size_t)4 * N;                          // N
    size_t aux = ((size_t)5 * N + 255) & ~(size_t)255;
    // zero-initialized region (contiguous):
    u64* confQ   = (u64*)(ws + aux);                         // 160
    u32* accCnt  = (u32*)(ws + aux + 160);                   // 80  -> 240
    u32* done    = (u32*)(ws + aux + 240);                   // 4   -> 256 (pad)
    u32* hist    = (u32*)(ws + aux + 256);                   // 57344 -> 57600
    u32* subhist = (u32*)(ws + aux + 57600);                 // 311296 -> 368896
    u32* meta    = (u32*)(ws + aux + 368896);                // 228
    size_t zbytes = 368896 + 228;

    hipMemsetAsync(ws + aux, 0, zbytes, stream);

    u32 W = (u32)(N / NBINS);

    if (C == 100) {
        k1_conf100<<<K1BLK, 256, 0, stream>>>(logits, labels, keys, accb, hist, N);
    } else {
        k1_generic<<<K1BLK, 256, 0, stream>>>(logits, labels, keys, accb, hist, N, C);
    }
    k2_scan   <<<1, 1024, 0, stream>>>(hist, meta, W);
    k3_subhist<<<1024, 256, 0, stream>>>(keys, meta, subhist, N);
    k4_resolve<<<NB, 256, 0, stream>>>(subhist, meta);
    k7_accum  <<<1024, 256, 0, stream>>>(keys, accb, meta, confQ, accCnt, done, out, N, W);
}

// Round 6
// 243.711 us; speedup vs baseline: 1.1212x; 1.1212x over previous
//
#include <hip/hip_runtime.h>
#include <stdint.h>

typedef uint32_t u32;
typedef uint64_t u64;
typedef uint8_t  u8;

#define KEY_MIN   0x3C000000u   /* conf = max softmax >= 1/C = 0.01 > 2^-7 */
#define SUBSHIFT  12
#define NBUCK     14336         /* (0x3F800000 - 0x3C000000) >> 12 */
#define SUBRANGE  4096
#define NBINS     20
#define NB        19

__device__ __forceinline__ u32 bucket_of(u32 key) {
    if (key < KEY_MIN) return 0u;
    u32 b = (key - KEY_MIN) >> SUBSHIFT;
    return b < (u32)NBUCK ? b : (u32)(NBUCK - 1);
}

// ---------------- K1 (C==100): 16 lanes/group, 2 rows/group, straight-line ----
// Block = 256 thr = 16 groups = 32 consecutive rows. All 4 float4 loads issue
// up-front (800B/group in flight); the two reduction chains are independent
// and interleaved for ds-pipe ILP. Non-persistent (block churn = free overlap).
__global__ __launch_bounds__(256) void k1_conf100(
        const float* __restrict__ logits, const int* __restrict__ labels,
        u32* __restrict__ keys, u8* __restrict__ accb, u32* __restrict__ hist,
        int N) {
    int lane = threadIdx.x & 63;
    int wid  = (blockIdx.x << 2) + (threadIdx.x >> 6);
    int g    = lane >> 4;
    int sub  = lane & 15;
    int gid  = wid * 4 + g;
    int rA   = gid * 2;
    if (rA >= N) return;
    int rB   = rA + 1;
    bool hasB = rB < N;
    bool has2 = sub < 9;                       // 25 float4/row: sub and sub+16
    const float4 NEG = make_float4(-3.4e38f, -3.4e38f, -3.4e38f, -3.4e38f);

    const float4* pA = (const float4*)(logits + (size_t)rA * 100);
    const float4* pB = (const float4*)(logits + (size_t)(hasB ? rB : rA) * 100);
    float4 a0 = pA[sub];
    float4 b0 = pB[sub];
    float4 a1 = has2 ? pA[sub + 16] : NEG;
    float4 b1 = has2 ? pB[sub + 16] : NEG;

    // in-lane max+argmax, FIRST-max semantics (strict >, ascending index)
    float mA = a0.x; int aA = 4 * sub;
    if (a0.y > mA) { mA = a0.y; aA = 4 * sub + 1; }
    if (a0.z > mA) { mA = a0.z; aA = 4 * sub + 2; }
    if (a0.w > mA) { mA = a0.w; aA = 4 * sub + 3; }
    float mB = b0.x; int aB = 4 * sub;
    if (b0.y > mB) { mB = b0.y; aB = 4 * sub + 1; }
    if (b0.z > mB) { mB = b0.z; aB = 4 * sub + 2; }
    if (b0.w > mB) { mB = b0.w; aB = 4 * sub + 3; }
    int c2 = 64 + 4 * sub;
    if (a1.x > mA) { mA = a1.x; aA = c2; }
    if (a1.y > mA) { mA = a1.y; aA = c2 + 1; }
    if (a1.z > mA) { mA = a1.z; aA = c2 + 2; }
    if (a1.w > mA) { mA = a1.w; aA = c2 + 3; }
    if (b1.x > mB) { mB = b1.x; aB = c2; }
    if (b1.y > mB) { mB = b1.y; aB = c2 + 1; }
    if (b1.z > mB) { mB = b1.z; aB = c2 + 2; }
    if (b1.w > mB) { mB = b1.w; aB = c2 + 3; }

    // 16-lane reductions, A/B interleaved (independent chains)
    #pragma unroll
    for (int off = 8; off >= 1; off >>= 1) {
        float oA = __shfl_xor(mA, off); int xA = __shfl_xor(aA, off);
        float oB = __shfl_xor(mB, off); int xB = __shfl_xor(aB, off);
        if (oA > mA || (oA == mA && xA < aA)) { mA = oA; aA = xA; }
        if (oB > mB || (oB == mB && xB < aB)) { mB = oB; aB = xB; }
    }

    float sA = __expf(a0.x - mA) + __expf(a0.y - mA) + __expf(a0.z - mA) + __expf(a0.w - mA);
    float sB = __expf(b0.x - mB) + __expf(b0.y - mB) + __expf(b0.z - mB) + __expf(b0.w - mB);
    if (has2) {
        sA += __expf(a1.x - mA) + __expf(a1.y - mA) + __expf(a1.z - mA) + __expf(a1.w - mA);
        sB += __expf(b1.x - mB) + __expf(b1.y - mB) + __expf(b1.z - mB) + __expf(b1.w - mB);
    }
    #pragma unroll
    for (int off = 8; off >= 1; off >>= 1) {
        sA += __shfl_xor(sA, off);
        sB += __shfl_xor(sB, off);
    }

    if (sub == 0) {
        u32 keyA = __float_as_uint(1.0f / sA);
        keys[rA] = keyA;
        accb[rA] = (labels[rA] == aA) ? (u8)1 : (u8)0;
        atomicAdd(&hist[bucket_of(keyA)], 1u);
        if (hasB) {
            u32 keyB = __float_as_uint(1.0f / sB);
            keys[rB] = keyB;
            accb[rB] = (labels[rB] == aB) ? (u8)1 : (u8)0;
            atomicAdd(&hist[bucket_of(keyB)], 1u);
        }
    }
}

// ---------------- K1 generic fallback -----------------------------------------
__global__ __launch_bounds__(256) void k1_generic(
        const float* __restrict__ logits, const int* __restrict__ labels,
        u32* __restrict__ keys, u8* __restrict__ accb, u32* __restrict__ hist,
        int N, int C) {
    int i = blockIdx.x * blockDim.x + threadIdx.x;
    if (i >= N) return;
    const float* row = logits + (size_t)i * (size_t)C;
    float m = -3.4e38f, s = 0.f;
    int am = 0;
    for (int c = 0; c < C; c++) {
        float v = row[c];
        float nm = fmaxf(m, v); am = (v > m) ? c : am;
        s = s * __expf(m - nm) + __expf(v - nm); m = nm;
    }
    float conf = 1.0f / s;
    u32 key = __float_as_uint(conf);
    keys[i] = key;
    accb[i] = (labels[i] == am) ? (u8)1 : (u8)0;
    atomicAdd(&hist[bucket_of(key)], 1u);
}

// meta: 0..18 bBucket | 19..37 bOff | 38..56 Kkey
// ---------------- K2: LDS-staged scan of hist, find boundary buckets ----------
__global__ __launch_bounds__(1024) void k2_scan(
        const u32* __restrict__ hist, u32* __restrict__ meta, u32 W) {
    __shared__ u32 lh[NBUCK];     // 56 KB
    __shared__ u32 sp[1024];      // 4 KB
    int t = threadIdx.x;
    #pragma unroll
    for (int k = 0; k < NBUCK / 1024; k++) lh[k * 1024 + t] = hist[k * 1024 + t];
    __syncthreads();
    const int PER = NBUCK / 1024;  // 14
    u32 s = 0;
    #pragma unroll
    for (int k = 0; k < PER; k++) s += lh[t * PER + k];
    sp[t] = s; __syncthreads();
    for (int d = 1; d < 1024; d <<= 1) {
        u32 v = (t >= d) ? sp[t - d] : 0u;
        __syncthreads(); sp[t] += v; __syncthreads();
    }
    u32 cum = sp[t] - s;
    for (int k = 0; k < PER; k++) {
        u32 c = lh[t * PER + k];
        if (c) {
            for (int j = 0; j < NB; j++) {
                u32 r = (u32)(j + 1) * W;
                if (cum < r && r <= cum + c) {
                    meta[j] = (u32)(t * PER + k);
                    meta[NB + j] = r - cum;
                }
            }
        }
        cum += c;
    }
}

// ---------------- K3: sub-histogram (low 12 bits) of boundary buckets ---------
__global__ __launch_bounds__(256) void k3_subhist(
        const u32* __restrict__ keys, const u32* __restrict__ meta,
        u32* __restrict__ subhist, int N) {
    __shared__ u32 sB[NB];
    if (threadIdx.x < NB) sB[threadIdx.x] = meta[threadIdx.x];
    __syncthreads();
    int total4 = N >> 2;
    const uint4* k4 = (const uint4*)keys;
    for (int i = blockIdx.x * blockDim.x + threadIdx.x; i < total4;
         i += gridDim.x * blockDim.x) {
        uint4 kv = k4[i];
        u32 ks[4] = {kv.x, kv.y, kv.z, kv.w};
        #pragma unroll
        for (int e = 0; e < 4; e++) {
            u32 b = bucket_of(ks[e]);
            #pragma unroll
            for (int j = 0; j < NB; j++)
                if (b == sB[j])
                    atomicAdd(&subhist[j * SUBRANGE + (ks[e] & (SUBRANGE - 1))], 1u);
        }
    }
    for (int i = (total4 << 2) + blockIdx.x * blockDim.x + threadIdx.x; i < N;
         i += gridDim.x * blockDim.x) {
        u32 k = keys[i];
        u32 b = bucket_of(k);
        for (int j = 0; j < NB; j++)
            if (b == sB[j])
                atomicAdd(&subhist[j * SUBRANGE + (k & (SUBRANGE - 1))], 1u);
    }
}

// ---------------- K4: resolve exact threshold keys (19 blocks x 256) ----------
__global__ __launch_bounds__(256) void k4_resolve(
        const u32* __restrict__ subhist, u32* __restrict__ meta) {
    int j = blockIdx.x;
    int t = threadIdx.x;
    __shared__ u32 sh[256];
    const uint4* s4 = (const uint4*)(subhist + j * SUBRANGE);
    uint4 v[4];
    #pragma unroll
    for (int q = 0; q < 4; q++) v[q] = s4[t * 4 + q];
    u32 tsum = 0;
    #pragma unroll
    for (int q = 0; q < 4; q++) tsum += v[q].x + v[q].y + v[q].z + v[q].w;
    sh[t] = tsum; __syncthreads();
    for (int d = 1; d < 256; d <<= 1) {
        u32 x = (t >= d) ? sh[t - d] : 0u;
        __syncthreads(); sh[t] += x; __syncthreads();
    }
    u32 run = sh[t] - tsum;
    u32 off = meta[NB + j];
    u32 bkt = meta[j];
    #pragma unroll
    for (int q = 0; q < 4; q++) {
        u32 e[4] = {v[q].x, v[q].y, v[q].z, v[q].w};
        #pragma unroll
        for (int c = 0; c < 4; c++) {
            if (run < off && off <= run + e[c])
                meta[2 * NB + j] = KEY_MIN + (bkt << SUBSHIFT) + (u32)(t * 16 + q * 4 + c);
            run += e[c];
        }
    }
}

// ---------------- K7: per-bin exact accumulation (per-wave LDS bins) ----------
__global__ __launch_bounds__(256) void k7_accum(
        const u32* __restrict__ keys, const u8* __restrict__ accb,
        const u32* __restrict__ meta, u64* __restrict__ confQ,
        u32* __restrict__ accCnt, int N) {
    __shared__ unsigned long long lc[4][NBINS];
    __shared__ u32 la[4][NBINS];
    __shared__ u32 sK[NB];
    int t = threadIdx.x;
    int w = t >> 6;
    if (t < 4 * NBINS) { lc[t / NBINS][t % NBINS] = 0ull; la[t / NBINS][t % NBINS] = 0u; }
    if (t < NB) sK[t] = meta[2 * NB + t];
    __syncthreads();
    int total4 = N >> 2;
    const uint4*  k4 = (const uint4*)keys;
    const uchar4* a4 = (const uchar4*)accb;
    for (int i = blockIdx.x * blockDim.x + t; i < total4; i += gridDim.x * blockDim.x) {
        uint4  kv = k4[i];
        uchar4 av = a4[i];
        u32 ks[4] = {kv.x, kv.y, kv.z, kv.w};
        u32 as[4] = {av.x, av.y, av.z, av.w};
        #pragma unroll
        for (int e = 0; e < 4; e++) {
            int bin = 0;
            #pragma unroll
            for (int j = 0; j < NB; j++) bin += (ks[e] > sK[j]) ? 1 : 0;
            u64 q = (u64)(__uint_as_float(ks[e]) * 4294967296.0f);  // exact shift
            atomicAdd(&lc[w][bin], (unsigned long long)q);
            atomicAdd(&la[w][bin], as[e]);
        }
    }
    for (int i = (total4 << 2) + blockIdx.x * blockDim.x + t; i < N;
         i += gridDim.x * blockDim.x) {
        u32 k = keys[i];
        int bin = 0;
        for (int j = 0; j < NB; j++) bin += (k > sK[j]) ? 1 : 0;
        u64 q = (u64)(__uint_as_float(k) * 4294967296.0f);
        atomicAdd(&lc[w][bin], (unsigned long long)q);
        atomicAdd(&la[w][bin], (u32)accb[i]);
    }
    __syncthreads();
    if (t < NBINS) {
        unsigned long long cq = lc[0][t] + lc[1][t] + lc[2][t] + lc[3][t];
        u32 ac = la[0][t] + la[1][t] + la[2][t] + la[3][t];
        if (cq) atomicAdd((unsigned long long*)&confQ[t], cq);
        if (ac) atomicAdd(&accCnt[t], ac);
    }
}

// ---------------- K8: final ECE -----------------------------------------------
__global__ void k8_final(const u64* __restrict__ confQ, const u32* __restrict__ accCnt,
                         float* __restrict__ out, int W, int N) {
    if (threadIdx.x == 0 && blockIdx.x == 0) {
        double ece = 0.0;
        for (int b = 0; b < NBINS; b++) {
            double cm = (double)confQ[b] * (1.0 / 4294967296.0) / (double)W;
            double am = (double)accCnt[b] / (double)W;
            ece += fabs(cm - am);
            out[1 + b] = (float)am;
        }
        out[0] = (float)(ece * (double)W / (double)N);
    }
}

extern "C" void kernel_launch(void* const* d_in, const int* in_sizes, int n_in,
                              void* d_out, int out_size, void* d_ws, size_t ws_size,
                              hipStream_t stream) {
    const float* logits = (const float*)d_in[0];
    const int*   labels = (const int*)d_in[1];
    int N = in_sizes[1];
    int C = in_sizes[0] / N;
    float* out = (float*)d_out;

    u8* ws = (u8*)d_ws;
    u32* keys = (u32*)ws;                                    // 4N
    u8*  accb = ws + (size_t)4 * N;                          // N
    size_t aux = ((size_t)5 * N + 255) & ~(size_t)255;
    // zero-initialized region (contiguous):
    u64* confQ   = (u64*)(ws + aux);                         // 160
    u32* accCnt  = (u32*)(ws + aux + 160);                   // 80  -> 240 (+16 pad)
    u32* hist    = (u32*)(ws + aux + 256);                   // 57344 -> 57600
    u32* subhist = (u32*)(ws + aux + 57600);                 // 311296 -> 368896
    u32* meta    = (u32*)(ws + aux + 368896);                // 228
    size_t zbytes = 368896 + 228;

    hipMemsetAsync(ws + aux, 0, zbytes, stream);

    u32 W = (u32)(N / NBINS);

    if (C == 100) {
        int blocks1 = (N + 31) / 32;   // 32 rows/block (16 groups x 2 rows)
        k1_conf100<<<blocks1, 256, 0, stream>>>(logits, labels, keys, accb, hist, N);
    } else {
        int blocks1 = (N + 255) / 256;
        k1_generic<<<blocks1, 256, 0, stream>>>(logits, labels, keys, accb, hist, N, C);
    }
    k2_scan   <<<1, 1024, 0, stream>>>(hist, meta, W);
    k3_subhist<<<1024, 256, 0, stream>>>(keys, meta, subhist, N);
    k4_resolve<<<NB, 256, 0, stream>>>(subhist, meta);
    k7_accum  <<<1024, 256, 0, stream>>>(keys, accb, meta, confQ, accCnt, N);
    k8_final  <<<1, 64, 0, stream>>>(confQ, accCnt, out, (int)W, N);
}

// Round 7
// 234.009 us; speedup vs baseline: 1.1677x; 1.0415x over previous
//
#include <hip/hip_runtime.h>
#include <stdint.h>

typedef uint32_t u32;
typedef uint64_t u64;
typedef uint8_t  u8;

#define KEY_MIN   0x3C000000u   /* conf = max softmax >= 1/C = 0.01 > 2^-7 */
#define SUBSHIFT  10
#define NBUCK     57344         /* (0x3F800000 - 0x3C000000) >> 10 */
#define NBINS     20
#define NB        19

__device__ __forceinline__ u32 bucket_of(u32 key) {
    if (key < KEY_MIN) return 0u;
    u32 b = (key - KEY_MIN) >> SUBSHIFT;
    return b < (u32)NBUCK ? b : (u32)(NBUCK - 1);
}

// ---------------- K1 (C==100): 16 lanes per row, coalesced (R4 champion) ------
__global__ __launch_bounds__(256) void k1_conf100(
        const float* __restrict__ logits, const int* __restrict__ labels,
        u32* __restrict__ keys, u8* __restrict__ accb, u32* __restrict__ hist,
        int N) {
    const int C4 = 25;
    int lane = threadIdx.x & 63;
    int wid  = (blockIdx.x * (blockDim.x >> 6)) + (threadIdx.x >> 6);
    int g    = lane >> 4;
    int sub  = lane & 15;
    int r    = wid * 4 + g;
    if (r >= N) return;

    const float4* row4 = (const float4*)(logits + (size_t)r * 100);
    float4 v0 = row4[sub];
    float4 v1;
    bool has2 = (sub + 16) < C4;
    if (has2) v1 = row4[sub + 16];
    else      v1 = make_float4(-3.4e38f, -3.4e38f, -3.4e38f, -3.4e38f);

    float m = v0.x; int am = 4 * sub;
    if (v0.y > m) { m = v0.y; am = 4 * sub + 1; }
    if (v0.z > m) { m = v0.z; am = 4 * sub + 2; }
    if (v0.w > m) { m = v0.w; am = 4 * sub + 3; }
    int b2 = 64 + 4 * sub;
    if (v1.x > m) { m = v1.x; am = b2; }
    if (v1.y > m) { m = v1.y; am = b2 + 1; }
    if (v1.z > m) { m = v1.z; am = b2 + 2; }
    if (v1.w > m) { m = v1.w; am = b2 + 3; }

    #pragma unroll
    for (int off = 8; off >= 1; off >>= 1) {
        float om = __shfl_xor(m, off);
        int   oa = __shfl_xor(am, off);
        if (om > m || (om == m && oa < am)) { m = om; am = oa; }
    }

    float s = __expf(v0.x - m) + __expf(v0.y - m) + __expf(v0.z - m) + __expf(v0.w - m);
    if (has2) s += __expf(v1.x - m) + __expf(v1.y - m) + __expf(v1.z - m) + __expf(v1.w - m);
    #pragma unroll
    for (int off = 8; off >= 1; off >>= 1) s += __shfl_xor(s, off);

    if (sub == 0) {
        float conf = 1.0f / s;
        u32 key = __float_as_uint(conf);
        keys[r] = key;
        accb[r] = (labels[r] == am) ? (u8)1 : (u8)0;
        atomicAdd(&hist[bucket_of(key)], 1u);
    }
}

// ---------------- K1 generic fallback -----------------------------------------
__global__ __launch_bounds__(256) void k1_generic(
        const float* __restrict__ logits, const int* __restrict__ labels,
        u32* __restrict__ keys, u8* __restrict__ accb, u32* __restrict__ hist,
        int N, int C) {
    int i = blockIdx.x * blockDim.x + threadIdx.x;
    if (i >= N) return;
    const float* row = logits + (size_t)i * (size_t)C;
    float m = -3.4e38f, s = 0.f;
    int am = 0;
    for (int c = 0; c < C; c++) {
        float v = row[c];
        float nm = fmaxf(m, v); am = (v > m) ? c : am;
        s = s * __expf(m - nm) + __expf(v - nm); m = nm;
    }
    float conf = 1.0f / s;
    u32 key = __float_as_uint(conf);
    keys[i] = key;
    accb[i] = (labels[i] == am) ? (u8)1 : (u8)0;
    atomicAdd(&hist[bucket_of(key)], 1u);
}

// meta: 0..18 bBucket | 19..37 bOff | 38..56 Kkey
// ---------------- K2: coalesced-sweep scan with running carry (NEW) -----------
// 56 sweeps; sweep i: thread t owns bucket i*1024+t (coalesced read).
// In-wave shfl scan + cross-wave LDS scan + block carry -> global exclusive
// prefix per bucket; 19 boundary checks done in-sweep.
__global__ __launch_bounds__(1024) void k2_scan(
        const u32* __restrict__ hist, u32* __restrict__ meta, u32 W) {
    __shared__ u32 wsum[16];
    __shared__ u32 carry_s;
    int t = threadIdx.x;
    int lane = t & 63;
    int w = t >> 6;                 // wave id, 0..15
    if (t == 0) carry_s = 0u;
    __syncthreads();

    const int SWEEPS = NBUCK / 1024;   // 56
    for (int i = 0; i < SWEEPS; i++) {
        u32 base = carry_s;            // carry from previous sweeps
        u32 v = hist[i * 1024 + t];
        // in-wave inclusive scan (64 lanes)
        u32 inc = v;
        #pragma unroll
        for (int d = 1; d < 64; d <<= 1) {
            u32 x = __shfl_up(inc, d);
            if (lane >= d) inc += x;
        }
        if (lane == 63) wsum[w] = inc;
        __syncthreads();
        u32 waveExcl = 0;
        for (int q = 0; q < w; q++) waveExcl += wsum[q];   // <=15 LDS broadcasts
        u32 cum = base + waveExcl + (inc - v);             // global exclusive prefix
        if (v) {
            for (int j = 0; j < NB; j++) {
                u32 r = (u32)(j + 1) * W;
                if (cum < r && r <= cum + v) {
                    meta[j] = (u32)(i * 1024 + t);    // boundary bucket
                    meta[NB + j] = r - cum;           // count of bucket below boundary
                }
            }
        }
        __syncthreads();
        if (t == 0) {
            u32 tot = 0;
            #pragma unroll
            for (int q = 0; q < 16; q++) tot += wsum[q];
            carry_s = base + tot;
        }
        __syncthreads();
    }
}

// ---------------- K3: sub-histogram (low 10 bits) of boundary buckets ---------
__global__ __launch_bounds__(256) void k3_subhist(
        const u32* __restrict__ keys, const u32* __restrict__ meta,
        u32* __restrict__ subhist, int N) {
    __shared__ u32 sB[NB];
    if (threadIdx.x < NB) sB[threadIdx.x] = meta[threadIdx.x];
    __syncthreads();
    int total4 = N >> 2;
    const uint4* k4 = (const uint4*)keys;
    for (int i = blockIdx.x * blockDim.x + threadIdx.x; i < total4;
         i += gridDim.x * blockDim.x) {
        uint4 kv = k4[i];
        u32 ks[4] = {kv.x, kv.y, kv.z, kv.w};
        #pragma unroll
        for (int e = 0; e < 4; e++) {
            u32 b = bucket_of(ks[e]);
            #pragma unroll
            for (int j = 0; j < NB; j++)
                if (b == sB[j]) atomicAdd(&subhist[j * 1024 + (ks[e] & 1023u)], 1u);
        }
    }
    for (int i = (total4 << 2) + blockIdx.x * blockDim.x + threadIdx.x; i < N;
         i += gridDim.x * blockDim.x) {
        u32 k = keys[i];
        u32 b = bucket_of(k);
        for (int j = 0; j < NB; j++)
            if (b == sB[j]) atomicAdd(&subhist[j * 1024 + (k & 1023u)], 1u);
    }
}

// ---------------- K4: resolve exact threshold keys (19 blocks x 256) ----------
__global__ void k4_resolve(const u32* __restrict__ subhist, u32* __restrict__ meta) {
    int j = blockIdx.x;
    int t = threadIdx.x;
    __shared__ u32 sh[256];
    u32 v[4];
    #pragma unroll
    for (int k = 0; k < 4; k++) v[k] = subhist[j * 1024 + t * 4 + k];
    u32 tsum = v[0] + v[1] + v[2] + v[3];
    sh[t] = tsum; __syncthreads();
    for (int d = 1; d < 256; d <<= 1) {
        u32 x = (t >= d) ? sh[t - d] : 0u;
        __syncthreads(); sh[t] += x; __syncthreads();
    }
    u32 run = sh[t] - tsum;
    u32 off = meta[NB + j];
    u32 bkt = meta[j];
    #pragma unroll
    for (int k = 0; k < 4; k++) {
        if (run < off && off <= run + v[k])
            meta[2 * NB + j] = KEY_MIN + (bkt << SUBSHIFT) + (u32)(t * 4 + k);
        run += v[k];
    }
}

// ---------------- K7: per-bin exact accumulation (per-wave LDS bins) ----------
__global__ __launch_bounds__(256) void k7_accum(
        const u32* __restrict__ keys, const u8* __restrict__ accb,
        const u32* __restrict__ meta, u64* __restrict__ confQ,
        u32* __restrict__ accCnt, int N) {
    __shared__ unsigned long long lc[4][NBINS];
    __shared__ u32 la[4][NBINS];
    __shared__ u32 sK[NB];
    int t = threadIdx.x;
    int w = t >> 6;
    if (t < 4 * NBINS) { lc[t / NBINS][t % NBINS] = 0ull; la[t / NBINS][t % NBINS] = 0u; }
    if (t < NB) sK[t] = meta[2 * NB + t];
    __syncthreads();
    int total4 = N >> 2;
    const uint4*  k4 = (const uint4*)keys;
    const uchar4* a4 = (const uchar4*)accb;
    for (int i = blockIdx.x * blockDim.x + t; i < total4; i += gridDim.x * blockDim.x) {
        uint4  kv = k4[i];
        uchar4 av = a4[i];
        u32 ks[4] = {kv.x, kv.y, kv.z, kv.w};
        u32 as[4] = {av.x, av.y, av.z, av.w};
        #pragma unroll
        for (int e = 0; e < 4; e++) {
            int bin = 0;
            #pragma unroll
            for (int j = 0; j < NB; j++) bin += (ks[e] > sK[j]) ? 1 : 0;
            u64 q = (u64)(__uint_as_float(ks[e]) * 4294967296.0f);  // exact shift
            atomicAdd(&lc[w][bin], (unsigned long long)q);
            atomicAdd(&la[w][bin], as[e]);
        }
    }
    for (int i = (total4 << 2) + blockIdx.x * blockDim.x + t; i < N;
         i += gridDim.x * blockDim.x) {
        u32 k = keys[i];
        int bin = 0;
        for (int j = 0; j < NB; j++) bin += (k > sK[j]) ? 1 : 0;
        u64 q = (u64)(__uint_as_float(k) * 4294967296.0f);
        atomicAdd(&lc[w][bin], (unsigned long long)q);
        atomicAdd(&la[w][bin], (u32)accb[i]);
    }
    __syncthreads();
    if (t < NBINS) {
        unsigned long long cq = lc[0][t] + lc[1][t] + lc[2][t] + lc[3][t];
        u32 ac = la[0][t] + la[1][t] + la[2][t] + la[3][t];
        if (cq) atomicAdd((unsigned long long*)&confQ[t], cq);
        if (ac) atomicAdd(&accCnt[t], ac);
    }
}

// ---------------- K8: final ECE -----------------------------------------------
__global__ void k8_final(const u64* __restrict__ confQ, const u32* __restrict__ accCnt,
                         float* __restrict__ out, int W, int N) {
    if (threadIdx.x == 0 && blockIdx.x == 0) {
        double ece = 0.0;
        for (int b = 0; b < NBINS; b++) {
            double cm = (double)confQ[b] * (1.0 / 4294967296.0) / (double)W;
            double am = (double)accCnt[b] / (double)W;
            ece += fabs(cm - am);
            out[1 + b] = (float)am;
        }
        out[0] = (float)(ece * (double)W / (double)N);
    }
}

extern "C" void kernel_launch(void* const* d_in, const int* in_sizes, int n_in,
                              void* d_out, int out_size, void* d_ws, size_t ws_size,
                              hipStream_t stream) {
    const float* logits = (const float*)d_in[0];
    const int*   labels = (const int*)d_in[1];
    int N = in_sizes[1];
    int C = in_sizes[0] / N;
    float* out = (float*)d_out;

    u8* ws = (u8*)d_ws;
    u32* keys = (u32*)ws;                                   // 4N
    u8*  accb = ws + (size_t)4 * N;                         // N
    size_t aux = ((size_t)5 * N + 255) & ~(size_t)255;
    // zero-initialized region:
    u64* confQ   = (u64*)(ws + aux);                        // 160
    u32* accCnt  = (u32*)(ws + aux + 160);                  // 80   -> 240 (+16 pad)
    u32* hist    = (u32*)(ws + aux + 256);                  // 229376 -> 229632
    u32* subhist = (u32*)(ws + aux + 229632);               // 77824  -> 307456
    u32* meta    = (u32*)(ws + aux + 307456);               // 3*NB*4 = 228
    size_t zbytes = 307456 + 228;

    hipMemsetAsync(ws + aux, 0, zbytes, stream);

    u32 W = (u32)(N / NBINS);

    if (C == 100) {
        int blocks1 = (N + 15) / 16;  // 16 rows/block: 4 waves x 4 row-groups
        k1_conf100<<<blocks1, 256, 0, stream>>>(logits, labels, keys, accb, hist, N);
    } else {
        int blocks1 = (N + 255) / 256;
        k1_generic<<<blocks1, 256, 0, stream>>>(logits, labels, keys, accb, hist, N, C);
    }
    k2_scan   <<<1, 1024, 0, stream>>>(hist, meta, W);
    k3_subhist<<<1024, 256, 0, stream>>>(keys, meta, subhist, N);
    k4_resolve<<<NB, 256, 0, stream>>>(subhist, meta);
    k7_accum  <<<1024, 256, 0, stream>>>(keys, accb, meta, confQ, accCnt, N);
    k8_final  <<<1, 64, 0, stream>>>(confQ, accCnt, out, (int)W, N);
}

// Round 8
// 193.187 us; speedup vs baseline: 1.4145x; 1.2113x over previous
//
#include <hip/hip_runtime.h>
#include <stdint.h>

typedef uint32_t u32;
typedef uint64_t u64;
typedef uint8_t  u8;

#define KEY_MIN   0x3C000000u   /* conf = max softmax >= 1/C = 0.01 > 2^-7 */
#define SUBSHIFT  10
#define NBUCK     57344         /* (0x3F800000 - 0x3C000000) >> 10 */
#define NBINS     20
#define NB        19

__device__ __forceinline__ u32 bucket_of(u32 key) {
    if (key < KEY_MIN) return 0u;
    u32 b = (key - KEY_MIN) >> SUBSHIFT;
    return b < (u32)NBUCK ? b : (u32)(NBUCK - 1);
}

// ---------------- K1 (C==100): 16 lanes/group, 4 rows/group straight-line -----
// Block = 256 thr = 16 groups = 64 consecutive rows. All 8 float4 loads issue
// before any reduction (6.4 KB in flight per wave); 4 independent reduce
// chains interleaved. Vectorized uint4/uchar4 epilogue stores.
__global__ __launch_bounds__(256) void k1_conf100(
        const float* __restrict__ logits, const int* __restrict__ labels,
        u32* __restrict__ keys, u8* __restrict__ accb, u32* __restrict__ hist,
        int N) {
    int lane = threadIdx.x & 63;
    int wid  = (blockIdx.x << 2) + (threadIdx.x >> 6);
    int g    = lane >> 4;
    int sub  = lane & 15;
    int gid  = wid * 4 + g;
    int r0   = gid * 4;
    if (r0 >= N) return;
    bool full = (r0 + 3) < N;
    bool has2 = sub < 9;                       // 25 float4/row: sub and sub+16
    const float4 NEG = make_float4(-3.4e38f, -3.4e38f, -3.4e38f, -3.4e38f);

    const float4* p0 = (const float4*)(logits + (size_t)r0 * 100);
    const float4* p1 = (const float4*)(logits + (size_t)(full ? r0 + 1 : r0) * 100);
    const float4* p2 = (const float4*)(logits + (size_t)(full ? r0 + 2 : r0) * 100);
    const float4* p3 = (const float4*)(logits + (size_t)(full ? r0 + 3 : r0) * 100);

    // all loads up-front (independent)
    float4 a0 = p0[sub], b0 = p1[sub], c0 = p2[sub], d0 = p3[sub];
    float4 a1 = has2 ? p0[sub + 16] : NEG;
    float4 b1 = has2 ? p1[sub + 16] : NEG;
    float4 c1 = has2 ? p2[sub + 16] : NEG;
    float4 d1 = has2 ? p3[sub + 16] : NEG;

    // in-lane max+argmax, FIRST-max semantics (strict >, ascending index)
    int i0 = 4 * sub, i2 = 64 + 4 * sub;
    float mA = a0.x; int aA = i0;
    float mB = b0.x; int aB = i0;
    float mC = c0.x; int aC = i0;
    float mD = d0.x; int aD = i0;
    if (a0.y > mA) { mA = a0.y; aA = i0 + 1; }
    if (b0.y > mB) { mB = b0.y; aB = i0 + 1; }
    if (c0.y > mC) { mC = c0.y; aC = i0 + 1; }
    if (d0.y > mD) { mD = d0.y; aD = i0 + 1; }
    if (a0.z > mA) { mA = a0.z; aA = i0 + 2; }
    if (b0.z > mB) { mB = b0.z; aB = i0 + 2; }
    if (c0.z > mC) { mC = c0.z; aC = i0 + 2; }
    if (d0.z > mD) { mD = d0.z; aD = i0 + 2; }
    if (a0.w > mA) { mA = a0.w; aA = i0 + 3; }
    if (b0.w > mB) { mB = b0.w; aB = i0 + 3; }
    if (c0.w > mC) { mC = c0.w; aC = i0 + 3; }
    if (d0.w > mD) { mD = d0.w; aD = i0 + 3; }
    if (a1.x > mA) { mA = a1.x; aA = i2; }
    if (b1.x > mB) { mB = b1.x; aB = i2; }
    if (c1.x > mC) { mC = c1.x; aC = i2; }
    if (d1.x > mD) { mD = d1.x; aD = i2; }
    if (a1.y > mA) { mA = a1.y; aA = i2 + 1; }
    if (b1.y > mB) { mB = b1.y; aB = i2 + 1; }
    if (c1.y > mC) { mC = c1.y; aC = i2 + 1; }
    if (d1.y > mD) { mD = d1.y; aD = i2 + 1; }
    if (a1.z > mA) { mA = a1.z; aA = i2 + 2; }
    if (b1.z > mB) { mB = b1.z; aB = i2 + 2; }
    if (c1.z > mC) { mC = c1.z; aC = i2 + 2; }
    if (d1.z > mD) { mD = d1.z; aD = i2 + 2; }
    if (a1.w > mA) { mA = a1.w; aA = i2 + 3; }
    if (b1.w > mB) { mB = b1.w; aB = i2 + 3; }
    if (c1.w > mC) { mC = c1.w; aC = i2 + 3; }
    if (d1.w > mD) { mD = d1.w; aD = i2 + 3; }

    // 16-lane reductions, 4 chains interleaved
    #pragma unroll
    for (int off = 8; off >= 1; off >>= 1) {
        float oA = __shfl_xor(mA, off); int xA = __shfl_xor(aA, off);
        float oB = __shfl_xor(mB, off); int xB = __shfl_xor(aB, off);
        float oC = __shfl_xor(mC, off); int xC = __shfl_xor(aC, off);
        float oD = __shfl_xor(mD, off); int xD = __shfl_xor(aD, off);
        if (oA > mA || (oA == mA && xA < aA)) { mA = oA; aA = xA; }
        if (oB > mB || (oB == mB && xB < aB)) { mB = oB; aB = xB; }
        if (oC > mC || (oC == mC && xC < aC)) { mC = oC; aC = xC; }
        if (oD > mD || (oD == mD && xD < aD)) { mD = oD; aD = xD; }
    }

    float sA = __expf(a0.x - mA) + __expf(a0.y - mA) + __expf(a0.z - mA) + __expf(a0.w - mA);
    float sB = __expf(b0.x - mB) + __expf(b0.y - mB) + __expf(b0.z - mB) + __expf(b0.w - mB);
    float sC = __expf(c0.x - mC) + __expf(c0.y - mC) + __expf(c0.z - mC) + __expf(c0.w - mC);
    float sD = __expf(d0.x - mD) + __expf(d0.y - mD) + __expf(d0.z - mD) + __expf(d0.w - mD);
    if (has2) {
        sA += __expf(a1.x - mA) + __expf(a1.y - mA) + __expf(a1.z - mA) + __expf(a1.w - mA);
        sB += __expf(b1.x - mB) + __expf(b1.y - mB) + __expf(b1.z - mB) + __expf(b1.w - mB);
        sC += __expf(c1.x - mC) + __expf(c1.y - mC) + __expf(c1.z - mC) + __expf(c1.w - mC);
        sD += __expf(d1.x - mD) + __expf(d1.y - mD) + __expf(d1.z - mD) + __expf(d1.w - mD);
    }
    #pragma unroll
    for (int off = 8; off >= 1; off >>= 1) {
        sA += __shfl_xor(sA, off);
        sB += __shfl_xor(sB, off);
        sC += __shfl_xor(sC, off);
        sD += __shfl_xor(sD, off);
    }

    if (sub == 0) {
        u32 kA = __float_as_uint(1.0f / sA);
        u32 kB = __float_as_uint(1.0f / sB);
        u32 kC = __float_as_uint(1.0f / sC);
        u32 kD = __float_as_uint(1.0f / sD);
        if (full) {
            *(uint4*)(keys + r0) = make_uint4(kA, kB, kC, kD);
            uchar4 ac;
            ac.x = (labels[r0]     == aA) ? 1 : 0;
            ac.y = (labels[r0 + 1] == aB) ? 1 : 0;
            ac.z = (labels[r0 + 2] == aC) ? 1 : 0;
            ac.w = (labels[r0 + 3] == aD) ? 1 : 0;
            *(uchar4*)(accb + r0) = ac;
            atomicAdd(&hist[bucket_of(kA)], 1u);
            atomicAdd(&hist[bucket_of(kB)], 1u);
            atomicAdd(&hist[bucket_of(kC)], 1u);
            atomicAdd(&hist[bucket_of(kD)], 1u);
        } else {
            u32 kk[4] = {kA, kB, kC, kD};
            int aa[4] = {aA, aB, aC, aD};
            for (int q = 0; q < 4 && r0 + q < N; q++) {
                keys[r0 + q] = kk[q];
                accb[r0 + q] = (labels[r0 + q] == aa[q]) ? (u8)1 : (u8)0;
                atomicAdd(&hist[bucket_of(kk[q])], 1u);
            }
        }
    }
}

// ---------------- K1 generic fallback -----------------------------------------
__global__ __launch_bounds__(256) void k1_generic(
        const float* __restrict__ logits, const int* __restrict__ labels,
        u32* __restrict__ keys, u8* __restrict__ accb, u32* __restrict__ hist,
        int N, int C) {
    int i = blockIdx.x * blockDim.x + threadIdx.x;
    if (i >= N) return;
    const float* row = logits + (size_t)i * (size_t)C;
    float m = -3.4e38f, s = 0.f;
    int am = 0;
    for (int c = 0; c < C; c++) {
        float v = row[c];
        float nm = fmaxf(m, v); am = (v > m) ? c : am;
        s = s * __expf(m - nm) + __expf(v - nm); m = nm;
    }
    float conf = 1.0f / s;
    u32 key = __float_as_uint(conf);
    keys[i] = key;
    accb[i] = (labels[i] == am) ? (u8)1 : (u8)0;
    atomicAdd(&hist[bucket_of(key)], 1u);
}

// meta: 0..18 bBucket | 19..37 bOff | 38..56 Kkey
// ---------------- K2: scan histogram (R4 scalar: max MLP, 1 block) ------------
__global__ void k2_scan(const u32* __restrict__ hist, u32* __restrict__ meta,
                        u32 W) {
    __shared__ u32 sp[1024];
    int t = threadIdx.x;
    const int PER = NBUCK / 1024;  // 56
    u32 s = 0;
    for (int k = 0; k < PER; k++) s += hist[t * PER + k];
    sp[t] = s; __syncthreads();
    for (int d = 1; d < 1024; d <<= 1) {
        u32 v = (t >= d) ? sp[t - d] : 0u;
        __syncthreads();
        sp[t] += v;
        __syncthreads();
    }
    u32 cum = sp[t] - s;  // exclusive prefix over this thread's 56 buckets
    for (int k = 0; k < PER; k++) {
        u32 c = hist[t * PER + k];
        if (c) {
            for (int j = 0; j < NB; j++) {
                u32 r = (u32)(j + 1) * W;
                if (cum < r && r <= cum + c) {
                    meta[j] = (u32)(t * PER + k);   // boundary bucket
                    meta[NB + j] = r - cum;         // samples of bucket below boundary
                }
            }
        }
        cum += c;
    }
}

// ---------------- K3: sub-histogram (low 10 bits) of boundary buckets ---------
__global__ __launch_bounds__(256) void k3_subhist(
        const u32* __restrict__ keys, const u32* __restrict__ meta,
        u32* __restrict__ subhist, int N) {
    __shared__ u32 sB[NB];
    if (threadIdx.x < NB) sB[threadIdx.x] = meta[threadIdx.x];
    __syncthreads();
    int total4 = N >> 2;
    const uint4* k4 = (const uint4*)keys;
    for (int i = blockIdx.x * blockDim.x + threadIdx.x; i < total4;
         i += gridDim.x * blockDim.x) {
        uint4 kv = k4[i];
        u32 ks[4] = {kv.x, kv.y, kv.z, kv.w};
        #pragma unroll
        for (int e = 0; e < 4; e++) {
            u32 b = bucket_of(ks[e]);
            #pragma unroll
            for (int j = 0; j < NB; j++)
                if (b == sB[j]) atomicAdd(&subhist[j * 1024 + (ks[e] & 1023u)], 1u);
        }
    }
    for (int i = (total4 << 2) + blockIdx.x * blockDim.x + threadIdx.x; i < N;
         i += gridDim.x * blockDim.x) {
        u32 k = keys[i];
        u32 b = bucket_of(k);
        for (int j = 0; j < NB; j++)
            if (b == sB[j]) atomicAdd(&subhist[j * 1024 + (k & 1023u)], 1u);
    }
}

// ---------------- K4: resolve exact threshold keys (19 blocks x 256) ----------
__global__ void k4_resolve(const u32* __restrict__ subhist, u32* __restrict__ meta) {
    int j = blockIdx.x;
    int t = threadIdx.x;
    __shared__ u32 sh[256];
    u32 v[4];
    #pragma unroll
    for (int k = 0; k < 4; k++) v[k] = subhist[j * 1024 + t * 4 + k];
    u32 tsum = v[0] + v[1] + v[2] + v[3];
    sh[t] = tsum; __syncthreads();
    for (int d = 1; d < 256; d <<= 1) {
        u32 x = (t >= d) ? sh[t - d] : 0u;
        __syncthreads(); sh[t] += x; __syncthreads();
    }
    u32 run = sh[t] - tsum;
    u32 off = meta[NB + j];
    u32 bkt = meta[j];
    #pragma unroll
    for (int k = 0; k < 4; k++) {
        if (run < off && off <= run + v[k])
            meta[2 * NB + j] = KEY_MIN + (bkt << SUBSHIFT) + (u32)(t * 4 + k);
        run += v[k];
    }
}

// ---------------- K7: per-bin exact accumulation (per-wave LDS bins) ----------
__global__ __launch_bounds__(256) void k7_accum(
        const u32* __restrict__ keys, const u8* __restrict__ accb,
        const u32* __restrict__ meta, u64* __restrict__ confQ,
        u32* __restrict__ accCnt, int N) {
    __shared__ unsigned long long lc[4][NBINS];
    __shared__ u32 la[4][NBINS];
    __shared__ u32 sK[NB];
    int t = threadIdx.x;
    int w = t >> 6;
    if (t < 4 * NBINS) { lc[t / NBINS][t % NBINS] = 0ull; la[t / NBINS][t % NBINS] = 0u; }
    if (t < NB) sK[t] = meta[2 * NB + t];
    __syncthreads();
    int total4 = N >> 2;
    const uint4*  k4 = (const uint4*)keys;
    const uchar4* a4 = (const uchar4*)accb;
    for (int i = blockIdx.x * blockDim.x + t; i < total4; i += gridDim.x * blockDim.x) {
        uint4  kv = k4[i];
        uchar4 av = a4[i];
        u32 ks[4] = {kv.x, kv.y, kv.z, kv.w};
        u32 as[4] = {av.x, av.y, av.z, av.w};
        #pragma unroll
        for (int e = 0; e < 4; e++) {
            int bin = 0;
            #pragma unroll
            for (int j = 0; j < NB; j++) bin += (ks[e] > sK[j]) ? 1 : 0;
            u64 q = (u64)(__uint_as_float(ks[e]) * 4294967296.0f);  // exact shift
            atomicAdd(&lc[w][bin], (unsigned long long)q);
            atomicAdd(&la[w][bin], as[e]);
        }
    }
    for (int i = (total4 << 2) + blockIdx.x * blockDim.x + t; i < N;
         i += gridDim.x * blockDim.x) {
        u32 k = keys[i];
        int bin = 0;
        for (int j = 0; j < NB; j++) bin += (k > sK[j]) ? 1 : 0;
        u64 q = (u64)(__uint_as_float(k) * 4294967296.0f);
        atomicAdd(&lc[w][bin], (unsigned long long)q);
        atomicAdd(&la[w][bin], (u32)accb[i]);
    }
    __syncthreads();
    if (t < NBINS) {
        unsigned long long cq = lc[0][t] + lc[1][t] + lc[2][t] + lc[3][t];
        u32 ac = la[0][t] + la[1][t] + la[2][t] + la[3][t];
        if (cq) atomicAdd((unsigned long long*)&confQ[t], cq);
        if (ac) atomicAdd(&accCnt[t], ac);
    }
}

// ---------------- K8: final ECE -----------------------------------------------
__global__ void k8_final(const u64* __restrict__ confQ, const u32* __restrict__ accCnt,
                         float* __restrict__ out, int W, int N) {
    if (threadIdx.x == 0 && blockIdx.x == 0) {
        double ece = 0.0;
        for (int b = 0; b < NBINS; b++) {
            double cm = (double)confQ[b] * (1.0 / 4294967296.0) / (double)W;
            double am = (double)accCnt[b] / (double)W;
            ece += fabs(cm - am);
            out[1 + b] = (float)am;
        }
        out[0] = (float)(ece * (double)W / (double)N);
    }
}

extern "C" void kernel_launch(void* const* d_in, const int* in_sizes, int n_in,
                              void* d_out, int out_size, void* d_ws, size_t ws_size,
                              hipStream_t stream) {
    const float* logits = (const float*)d_in[0];
    const int*   labels = (const int*)d_in[1];
    int N = in_sizes[1];
    int C = in_sizes[0] / N;
    float* out = (float*)d_out;

    u8* ws = (u8*)d_ws;
    u32* keys = (u32*)ws;                                   // 4N
    u8*  accb = ws + (size_t)4 * N;                         // N
    size_t aux = ((size_t)5 * N + 255) & ~(size_t)255;
    // zero-initialized region:
    u64* confQ   = (u64*)(ws + aux);                        // 160
    u32* accCnt  = (u32*)(ws + aux + 160);                  // 80   -> 240 (+16 pad)
    u32* hist    = (u32*)(ws + aux + 256);                  // 229376 -> 229632
    u32* subhist = (u32*)(ws + aux + 229632);               // 77824  -> 307456
    u32* meta    = (u32*)(ws + aux + 307456);               // 3*NB*4 = 228
    size_t zbytes = 307456 + 228;

    hipMemsetAsync(ws + aux, 0, zbytes, stream);

    u32 W = (u32)(N / NBINS);

    if (C == 100) {
        int blocks1 = (N + 63) / 64;  // 64 rows/block: 16 groups x 4 rows
        k1_conf100<<<blocks1, 256, 0, stream>>>(logits, labels, keys, accb, hist, N);
    } else {
        int blocks1 = (N + 255) / 256;
        k1_generic<<<blocks1, 256, 0, stream>>>(logits, labels, keys, accb, hist, N, C);
    }
    k2_scan   <<<1, 1024, 0, stream>>>(hist, meta, W);
    k3_subhist<<<1024, 256, 0, stream>>>(keys, meta, subhist, N);
    k4_resolve<<<NB, 256, 0, stream>>>(subhist, meta);
    k7_accum  <<<1024, 256, 0, stream>>>(keys, accb, meta, confQ, accCnt, N);
    k8_final  <<<1, 64, 0, stream>>>(confQ, accCnt, out, (int)W, N);
}